// Round 13
// baseline (781.085 us; speedup 1.0000x reference)
//
#include <hip/hip_runtime.h>
#include <hip/hip_bf16.h>
#include <stdint.h>

// BatchedLoRALinear: out[m][o] = sum_k x[m][k] W[o][k] + b[o] + 2*sum_r Bb[o][r] inter[m][r]
// M=16384, N=4096, K=4096 (+1 LoRA K-tile). bf16 MFMA, 256x256 tile, BK=64, 8 waves.
// R13 = R12 + merged 2-phase/K-tile (4 barriers instead of 8):
//  PhaseA: stage A1(t+1); BAR; lgkm0; rd fb1; Q1; lgkm0; rd a1; Q2; BAR
//  PhaseB: stage A0,B0,B1(t+2); vmcnt6; BAR; lgkm0; rd a0(t+1); Q3,Q4; rd fb0(t+1); BAR
// Ledger: gate keeps {A0,B0,B1}(t+2), drains A1(t+1)+older -> tile t+1 complete at
// PhaseB barrier. WAR-safe: only dead fragments pre-read (fb0(t+1) after Q3 uses fb0(t)).

typedef __attribute__((ext_vector_type(8))) short bf16x8;
typedef __attribute__((ext_vector_type(4))) float f32x4;
typedef __attribute__((ext_vector_type(8))) unsigned short ushort8;

#define MM    16384
#define DIN   4096
#define DOUT  4096
#define RR    16
#define NAD   32

__device__ __forceinline__ unsigned short f2bf(float f) {
    union { float f; unsigned int u; } v; v.f = f;
    unsigned int r = (v.u + 0x7FFFu + ((v.u >> 16) & 1u)) >> 16;  // RNE
    return (unsigned short)r;
}

__device__ __forceinline__ void gld16(const void* g, void* l) {
    __builtin_amdgcn_global_load_lds(
        (const __attribute__((address_space(1))) void*)g,
        (__attribute__((address_space(3))) void*)l,
        16, 0, 0);
}

#define BARRIER() __builtin_amdgcn_s_barrier()
#define SFENCE()  __builtin_amdgcn_sched_barrier(0)
#define LGKM0()   do { asm volatile("s_waitcnt lgkmcnt(0)" ::: "memory"); SFENCE(); } while (0)
#define WCNT6()   asm volatile("s_waitcnt vmcnt(6)" ::: "memory")
#define WCNT0()   asm volatile("s_waitcnt vmcnt(0)" ::: "memory")

// ---------- fp32 -> bf16 bulk convert (NT loads: sources read exactly once) ----------
__global__ __launch_bounds__(256) void cvt_kernel(const float* __restrict__ src,
                                                  unsigned short* __restrict__ dst,
                                                  long n) {
    long i0 = ((long)blockIdx.x * 256 + threadIdx.x) * 8;
    long stride = (long)gridDim.x * 256 * 8;
    for (long i = i0; i < n; i += stride) {
        f32x4 f0 = __builtin_nontemporal_load((const f32x4*)(src + i));
        f32x4 f1 = __builtin_nontemporal_load((const f32x4*)(src + i + 4));
        ushort8 o;
        o[0] = f2bf(f0[0]); o[1] = f2bf(f0[1]); o[2] = f2bf(f0[2]); o[3] = f2bf(f0[3]);
        o[4] = f2bf(f1[0]); o[5] = f2bf(f1[1]); o[6] = f2bf(f1[2]); o[7] = f2bf(f1[3]);
        *(ushort8*)(dst + i) = o;
    }
}

// ---------- B_all fp32 (NAD,DOUT,16) -> bf16 [NAD][DOUT][32] (cols 16..31 zero); zero Zrow ----------
__global__ __launch_bounds__(256) void cvt_ball_kernel(const float* __restrict__ Ball,
                                                       unsigned short* __restrict__ Bbf,
                                                       unsigned short* __restrict__ Zrow) {
    int row = blockIdx.x * 256 + threadIdx.x;
    const float* s = Ball + (size_t)row * RR;
    ushort8 o0, o1, z;
    #pragma unroll
    for (int j = 0; j < 8; ++j) {
        o0[j] = f2bf(__builtin_nontemporal_load(s + j));
        o1[j] = f2bf(__builtin_nontemporal_load(s + 8 + j));
        z[j] = 0;
    }
    ushort8* d = (ushort8*)(Bbf + (size_t)row * 32);
    d[0] = o0; d[1] = o1; d[2] = z; d[3] = z;
    if (row == 0) *(ushort8*)Zrow = z;
}

// ---------- inter[m][r] = 2 * sum_k x[m][k] * A_b[r][k], bf16, padded to 32 cols ----------
__global__ __launch_bounds__(256) void inter_kernel(const unsigned short* __restrict__ Xbf,
                                                    const unsigned short* __restrict__ Abf,
                                                    const int* __restrict__ ids,
                                                    unsigned short* __restrict__ Ibf) {
    int tid = threadIdx.x, w = tid >> 6, lane = tid & 63;
    int m0 = blockIdx.x * 64 + w * 16;
    int aid = ids[m0 >> 9];
    int lr = lane & 15, lk = (lane >> 4) * 8;
    const unsigned short* xp = Xbf + (size_t)(m0 + lr) * DIN + lk;
    const unsigned short* ap = Abf + ((size_t)aid * RR + lr) * DIN + lk;
    f32x4 acc = {};
    #pragma unroll 4
    for (int k = 0; k < DIN; k += 32) {
        bf16x8 a  = *(const bf16x8*)(xp + k);
        bf16x8 bb = *(const bf16x8*)(ap + k);
        acc = __builtin_amdgcn_mfma_f32_16x16x32_bf16(a, bb, acc, 0, 0, 0);
    }
    int rbase = m0 + (lane >> 4) * 4;
    #pragma unroll
    for (int r = 0; r < 4; ++r) {
        int m = rbase + r;
        Ibf[(size_t)m * 32 + lr]      = f2bf(acc[r] * 2.0f);
        Ibf[(size_t)m * 32 + 16 + lr] = 0;
    }
}

// ---------- general stage (prologue + LoRA tile 64; guard skips t>64) ----------
template<int HT>
__device__ __forceinline__ void stage_half(int t, unsigned short* region, int tid,
    const unsigned short* __restrict__ Xbf, const unsigned short* __restrict__ Wbf,
    const unsigned short* __restrict__ Ibf, const unsigned short* __restrict__ BbfA,
    const unsigned short* __restrict__ Zrow, int m0, int n0) {
    if (t > 64) return;
    #pragma unroll
    for (int j = 0; j < 2; ++j) {
        int r = j * 64 + (tid >> 3);
        int gr;
        if (HT == 0)      gr = r + (r & 64);
        else if (HT == 1) gr = 64 + r + (r & 64);
        else if (HT == 2) gr = ((r >> 5) << 6) | (r & 31);
        else              gr = (((r >> 5) << 6) | (r & 31)) + 32;
        int c = ((tid & 7) ^ (r & 7)) * 8;   // T2: 3-bit slot XOR, involution with read side
        const unsigned short* src;
        if (t < 64) {
            src = (HT <= 1 ? Xbf + (size_t)(m0 + gr) * DIN
                           : Wbf + (size_t)(n0 + gr) * DIN) + (size_t)t * 64 + c;
        } else {
            if (c >= 32) src = Zrow;  // logical cols 32..63 are zero
            else src = (HT <= 1 ? Ibf + (size_t)(m0 + gr) * 32
                                : BbfA + (size_t)(n0 + gr) * 32) + c;
        }
        gld16(src, region + r * 64 + (tid & 7) * 8);
    }
}

__device__ __forceinline__ void readA(bf16x8 (&A)[4][2], const char* p, int hk16, int xsw) {
    #pragma unroll
    for (int fi = 0; fi < 4; ++fi)
        #pragma unroll
        for (int ks = 0; ks < 2; ++ks)
            A[fi][ks] = *(const bf16x8*)(p + fi * 2048 + ((ks * 64 + hk16) ^ xsw));
}
__device__ __forceinline__ void readB(bf16x8 (&B)[2][2], const char* p, int hk16, int xsw) {
    #pragma unroll
    for (int fj = 0; fj < 2; ++fj)
        #pragma unroll
        for (int ks = 0; ks < 2; ++ks)
            B[fj][ks] = *(const bf16x8*)(p + fj * 2048 + ((ks * 64 + hk16) ^ xsw));
}

template<int RO, int CO>
__device__ __forceinline__ void quad(f32x4 (&acc)[8][4], const bf16x8 (&A)[4][2], const bf16x8 (&B)[2][2]) {
    #pragma unroll
    for (int fi = 0; fi < 4; ++fi)
        #pragma unroll
        for (int fj = 0; fj < 2; ++fj)
            #pragma unroll
            for (int ks = 0; ks < 2; ++ks)
                acc[RO + fi][CO + fj] = __builtin_amdgcn_mfma_f32_16x16x32_bf16(
                    A[fi][ks], B[fj][ks], acc[RO + fi][CO + fj], 0, 0, 0);
}

// ---------- main GEMM: 256x256 tile, BK=64, 8 waves (2x4), merged 2-phase/K-tile ----------
__global__ __launch_bounds__(512, 2) void gemm8_kernel(
    const unsigned short* __restrict__ Xbf, const unsigned short* __restrict__ Wbf,
    const unsigned short* __restrict__ Ibf, const unsigned short* __restrict__ Bbf,
    const unsigned short* __restrict__ Zrow,
    const float* __restrict__ bias, const int* __restrict__ ids,
    float* __restrict__ out) {
    __shared__ unsigned short lds[2][2][2][8192];  // [buf][A/B][half][128*64]

    int tid = threadIdx.x;
    int bid = blockIdx.x;
    // bm-range XCD swizzle: XCD x = bid&7 owns bm in [8x, 8x+8), all 16 bn, bn-fastest.
    int xcd = bid & 7, q = bid >> 3;
    int bm = xcd * 8 + (q >> 4), bn = q & 15;
    int m0 = bm << 8, n0 = bn << 8;
    int aid = ids[m0 >> 9];                   // 256-row tile within one 512-row batch
    const unsigned short* BbfA = Bbf + (size_t)aid * DOUT * 32;

    int w = tid >> 6, l = tid & 63;
    int wr = w >> 2, wc = w & 3;              // 2 x 4 waves, each owns 128x64 of C
    int lr = l & 15;
    int hk16 = (l >> 4) * 16;                 // k-offset bytes per lane group
    int xsw = (l & 7) << 4;                   // read-side 3-bit slot swizzle (row&7 == l&7)

    // ---- hoisted staging addresses: 8 per-thread base pointers, +t*64 elems per tile ----
    int r0 = tid >> 3;
    int cc = ((tid & 7) ^ (r0 & 7)) * 8;      // same for j=0/1 (since (64+r0)&7 == r0&7)
    int g2 = ((r0 >> 5) << 6) | (r0 & 31);
    const unsigned short* pA0 = Xbf + (size_t)(m0 + r0) * DIN + cc;        // HT0 j0
    const unsigned short* pA1 = Xbf + (size_t)(m0 + 128 + r0) * DIN + cc;  // HT0 j1
    const unsigned short* pA2 = Xbf + (size_t)(m0 + 64 + r0) * DIN + cc;   // HT1 j0
    const unsigned short* pA3 = Xbf + (size_t)(m0 + 192 + r0) * DIN + cc;  // HT1 j1
    const unsigned short* pB0 = Wbf + (size_t)(n0 + g2) * DIN + cc;        // HT2 j0
    const unsigned short* pB1 = Wbf + (size_t)(n0 + 128 + g2) * DIN + cc;  // HT2 j1
    const unsigned short* pB2 = Wbf + (size_t)(n0 + 32 + g2) * DIN + cc;   // HT3 j0
    const unsigned short* pB3 = Wbf + (size_t)(n0 + 160 + g2) * DIN + cc;  // HT3 j1
    int dof = tid * 8;                        // linear LDS dst (gld16: base + lane*16B)

    f32x4 acc[8][4] = {};
    bf16x8 a0[4][2], a1[4][2], fb0[2][2], fb1[2][2];  // persistent fragment buffers

    // prologue: T0 complete -> buf0; T1 {A0,B0,B1} -> buf1; 3 half-tiles in flight
    stage_half<0>(0, &lds[0][0][0][0], tid, Xbf, Wbf, Ibf, BbfA, Zrow, m0, n0);
    stage_half<1>(0, &lds[0][0][1][0], tid, Xbf, Wbf, Ibf, BbfA, Zrow, m0, n0);
    stage_half<2>(0, &lds[0][1][0][0], tid, Xbf, Wbf, Ibf, BbfA, Zrow, m0, n0);
    stage_half<3>(0, &lds[0][1][1][0], tid, Xbf, Wbf, Ibf, BbfA, Zrow, m0, n0);
    stage_half<0>(1, &lds[1][0][0][0], tid, Xbf, Wbf, Ibf, BbfA, Zrow, m0, n0);
    stage_half<2>(1, &lds[1][1][0][0], tid, Xbf, Wbf, Ibf, BbfA, Zrow, m0, n0);
    stage_half<3>(1, &lds[1][1][1][0], tid, Xbf, Wbf, Ibf, BbfA, Zrow, m0, n0);
    WCNT6(); BARRIER();

    int rowA = (wr * 64 + lr) * 128;  // byte offset of this lane's A rows in a half-region
    int rowB = (wc * 32 + lr) * 128;

    // pipeline prime: a0(0), fb0(0) from buf0 (landed by prologue gate)
    readA(a0, (const char*)&lds[0][0][0][0] + rowA, hk16, xsw);
    readB(fb0, (const char*)&lds[0][1][0][0] + rowB, hk16, xsw);

    #pragma unroll 2
    for (int t = 0; t < 64; ++t) {
        int b = t & 1;

        // ---- PhaseA: stage A1(t+1)->buf[b^1]; Q1 + Q2 with interleaved reads ----
        {
            unsigned short* d = &lds[b ^ 1][0][1][0] + dof;
            if (t < 63) { gld16(pA2 + (size_t)(t + 1) * 64, d);
                          gld16(pA3 + (size_t)(t + 1) * 64, d + 4096); }
            else stage_half<1>(t + 1, &lds[b ^ 1][0][1][0], tid, Xbf, Wbf, Ibf, BbfA, Zrow, m0, n0);
        }
        BARRIER();
        LGKM0();                                   // drains a0(t), fb0(t)
        readB(fb1, (const char*)&lds[b][1][1][0] + rowB, hk16, xsw);
        SFENCE();                                  // issue fb1 before Q1 (hide under MFMA)
        __builtin_amdgcn_s_setprio(1);
        quad<0, 0>(acc, a0, fb0);
        __builtin_amdgcn_s_setprio(0);
        LGKM0();                                   // drains fb1
        readA(a1, (const char*)&lds[b][0][1][0] + rowA, hk16, xsw);
        SFENCE();                                  // issue a1 before Q2
        __builtin_amdgcn_s_setprio(1);
        quad<0, 2>(acc, a0, fb1);
        __builtin_amdgcn_s_setprio(0);
        BARRIER();

        // ---- PhaseB: stage A0,B0,B1(t+2)->buf[b]; vmcnt gate; Q3 + Q4 ----
        {
            unsigned short* d = &lds[b][0][0][0] + dof;
            if (t < 62) { gld16(pA0 + (size_t)(t + 2) * 64, d);
                          gld16(pA1 + (size_t)(t + 2) * 64, d + 4096); }
            else stage_half<0>(t + 2, &lds[b][0][0][0], tid, Xbf, Wbf, Ibf, BbfA, Zrow, m0, n0);
        }
        {
            unsigned short* d = &lds[b][1][0][0] + dof;
            if (t < 62) { gld16(pB0 + (size_t)(t + 2) * 64, d);
                          gld16(pB1 + (size_t)(t + 2) * 64, d + 4096); }
            else stage_half<2>(t + 2, &lds[b][1][0][0], tid, Xbf, Wbf, Ibf, BbfA, Zrow, m0, n0);
        }
        {
            unsigned short* d = &lds[b][1][1][0] + dof;
            if (t < 62) { gld16(pB2 + (size_t)(t + 2) * 64, d);
                          gld16(pB3 + (size_t)(t + 2) * 64, d + 4096); }
            else stage_half<3>(t + 2, &lds[b][1][1][0], tid, Xbf, Wbf, Ibf, BbfA, Zrow, m0, n0);
        }
        if (t == 63) { WCNT0(); } else { WCNT6(); }
        BARRIER();
        LGKM0();                                   // drains a1(t)
        readA(a0, (const char*)&lds[b ^ 1][0][0][0] + rowA, hk16, xsw);  // a0 dead since Q2
        SFENCE();                                  // issue a0(t+1) before Q3/Q4
        __builtin_amdgcn_s_setprio(1);
        quad<4, 0>(acc, a1, fb0);                  // consumes fb0(t) — so fb0 read comes after
        quad<4, 2>(acc, a1, fb1);
        __builtin_amdgcn_s_setprio(0);
        readB(fb0, (const char*)&lds[b ^ 1][1][0][0] + rowB, hk16, xsw);
        BARRIER();
    }

    // tail: LoRA K-tile 64 in buf0; a0(64), fb0(64) reads outstanding
    LGKM0();
    quad<0, 0>(acc, a0, fb0);
    readB(fb1, (const char*)&lds[0][1][1][0] + rowB, hk16, xsw);
    readA(a1, (const char*)&lds[0][0][1][0] + rowA, hk16, xsw);
    LGKM0();
    quad<0, 2>(acc, a0, fb1);
    quad<4, 0>(acc, a1, fb0);
    quad<4, 2>(acc, a1, fb1);

    // epilogue: + bias, fp32 NT store. C/D frag layout: col = lane&15, row = (lane>>4)*4 + reg
    #pragma unroll
    for (int cj = 0; cj < 4; ++cj) {
        int col = n0 + wc * 64 + cj * 16 + lr;
        float bv = bias[col];
        #pragma unroll
        for (int ri = 0; ri < 8; ++ri) {
            size_t mrow = (size_t)(m0 + wr * 128 + ri * 16 + (l >> 4) * 4);
            float* op = out + mrow * DOUT + col;
            #pragma unroll
            for (int r = 0; r < 4; ++r)
                __builtin_nontemporal_store(acc[ri][cj][r] + bv, op + (size_t)r * DOUT);
        }
    }
}

extern "C" void kernel_launch(void* const* d_in, const int* in_sizes, int n_in,
                              void* d_out, int out_size, void* d_ws, size_t ws_size,
                              hipStream_t stream) {
    const float* x     = (const float*)d_in[0];   // (32,512,4096)
    const int*   ids   = (const int*)d_in[1];     // (32,)
    const float* A_all = (const float*)d_in[2];   // (32,16,4096)
    const float* B_all = (const float*)d_in[3];   // (32,4096,16)
    const float* W     = (const float*)d_in[4];   // (4096,4096)
    const float* bias  = (const float*)d_in[5];   // (4096,)
    float* out = (float*)d_out;                   // (32,512,4096) fp32

    unsigned short* Xbf  = (unsigned short*)d_ws;            // [16384][4096]
    unsigned short* Wbf  = Xbf + (size_t)MM * DIN;           // [4096][4096]
    unsigned short* Abf  = Wbf + (size_t)DOUT * DIN;         // [32][16][4096]
    unsigned short* Bbf  = Abf + (size_t)NAD * RR * DIN;     // [32][4096][32]
    unsigned short* Ibf  = Bbf + (size_t)NAD * DOUT * 32;    // [16384][32]
    unsigned short* Zrow = Ibf + (size_t)MM * 32;            // 8 zero elems (16B)

    cvt_kernel<<<8192, 256, 0, stream>>>(x, Xbf, (long)MM * DIN);
    cvt_kernel<<<8192, 256, 0, stream>>>(W, Wbf, (long)DOUT * DIN);
    cvt_kernel<<<1024, 256, 0, stream>>>(A_all, Abf, (long)NAD * RR * DIN);
    cvt_ball_kernel<<<512, 256, 0, stream>>>(B_all, Bbf, Zrow);
    inter_kernel<<<256, 256, 0, stream>>>(Xbf, Abf, ids, Ibf);
    gemm8_kernel<<<1024, 512, 0, stream>>>(Xbf, Wbf, Ibf, Bbf, Zrow, bias, ids, out);
}

// Round 14
// 572.480 us; speedup vs baseline: 1.3644x; 1.3644x over previous
//
#include <hip/hip_runtime.h>
#include <hip/hip_bf16.h>
#include <stdint.h>

// BatchedLoRALinear: out[m][o] = sum_k x[m][k] W[o][k] + b[o] + 2*sum_r Bb[o][r] inter[m][r]
// M=16384, N=4096, K=4096 (+1 LoRA K-tile). bf16 MFMA, 256x256 tile, BK=64, 8 waves.
// R14 = R12 (best, 503us gemm) with the main loop peeled: t in [0,62) branchless
// staging via hoisted pointers; t=62 and t=63 peeled replicating R12's exact paths
// (general stage_half for LoRA tile 64, WCNT0 drain at t=63). Sync graph unchanged.

typedef __attribute__((ext_vector_type(8))) short bf16x8;
typedef __attribute__((ext_vector_type(4))) float f32x4;
typedef __attribute__((ext_vector_type(8))) unsigned short ushort8;

#define MM    16384
#define DIN   4096
#define DOUT  4096
#define RR    16
#define NAD   32

__device__ __forceinline__ unsigned short f2bf(float f) {
    union { float f; unsigned int u; } v; v.f = f;
    unsigned int r = (v.u + 0x7FFFu + ((v.u >> 16) & 1u)) >> 16;  // RNE
    return (unsigned short)r;
}

__device__ __forceinline__ void gld16(const void* g, void* l) {
    __builtin_amdgcn_global_load_lds(
        (const __attribute__((address_space(1))) void*)g,
        (__attribute__((address_space(3))) void*)l,
        16, 0, 0);
}

#define BARRIER() __builtin_amdgcn_s_barrier()
#define SFENCE()  __builtin_amdgcn_sched_barrier(0)
#define LGKM0()   do { asm volatile("s_waitcnt lgkmcnt(0)" ::: "memory"); SFENCE(); } while (0)
#define WCNT6()   asm volatile("s_waitcnt vmcnt(6)" ::: "memory")
#define WCNT0()   asm volatile("s_waitcnt vmcnt(0)" ::: "memory")

// ---------- fp32 -> bf16 bulk convert (NT loads: sources read exactly once) ----------
__global__ __launch_bounds__(256) void cvt_kernel(const float* __restrict__ src,
                                                  unsigned short* __restrict__ dst,
                                                  long n) {
    long i0 = ((long)blockIdx.x * 256 + threadIdx.x) * 8;
    long stride = (long)gridDim.x * 256 * 8;
    for (long i = i0; i < n; i += stride) {
        f32x4 f0 = __builtin_nontemporal_load((const f32x4*)(src + i));
        f32x4 f1 = __builtin_nontemporal_load((const f32x4*)(src + i + 4));
        ushort8 o;
        o[0] = f2bf(f0[0]); o[1] = f2bf(f0[1]); o[2] = f2bf(f0[2]); o[3] = f2bf(f0[3]);
        o[4] = f2bf(f1[0]); o[5] = f2bf(f1[1]); o[6] = f2bf(f1[2]); o[7] = f2bf(f1[3]);
        *(ushort8*)(dst + i) = o;
    }
}

// ---------- B_all fp32 (NAD,DOUT,16) -> bf16 [NAD][DOUT][32] (cols 16..31 zero); zero Zrow ----------
__global__ __launch_bounds__(256) void cvt_ball_kernel(const float* __restrict__ Ball,
                                                       unsigned short* __restrict__ Bbf,
                                                       unsigned short* __restrict__ Zrow) {
    int row = blockIdx.x * 256 + threadIdx.x;
    const float* s = Ball + (size_t)row * RR;
    ushort8 o0, o1, z;
    #pragma unroll
    for (int j = 0; j < 8; ++j) {
        o0[j] = f2bf(__builtin_nontemporal_load(s + j));
        o1[j] = f2bf(__builtin_nontemporal_load(s + 8 + j));
        z[j] = 0;
    }
    ushort8* d = (ushort8*)(Bbf + (size_t)row * 32);
    d[0] = o0; d[1] = o1; d[2] = z; d[3] = z;
    if (row == 0) *(ushort8*)Zrow = z;
}

// ---------- inter[m][r] = 2 * sum_k x[m][k] * A_b[r][k], bf16, padded to 32 cols ----------
__global__ __launch_bounds__(256) void inter_kernel(const unsigned short* __restrict__ Xbf,
                                                    const unsigned short* __restrict__ Abf,
                                                    const int* __restrict__ ids,
                                                    unsigned short* __restrict__ Ibf) {
    int tid = threadIdx.x, w = tid >> 6, lane = tid & 63;
    int m0 = blockIdx.x * 64 + w * 16;
    int aid = ids[m0 >> 9];
    int lr = lane & 15, lk = (lane >> 4) * 8;
    const unsigned short* xp = Xbf + (size_t)(m0 + lr) * DIN + lk;
    const unsigned short* ap = Abf + ((size_t)aid * RR + lr) * DIN + lk;
    f32x4 acc = {};
    #pragma unroll 4
    for (int k = 0; k < DIN; k += 32) {
        bf16x8 a  = *(const bf16x8*)(xp + k);
        bf16x8 bb = *(const bf16x8*)(ap + k);
        acc = __builtin_amdgcn_mfma_f32_16x16x32_bf16(a, bb, acc, 0, 0, 0);
    }
    int rbase = m0 + (lane >> 4) * 4;
    #pragma unroll
    for (int r = 0; r < 4; ++r) {
        int m = rbase + r;
        Ibf[(size_t)m * 32 + lr]      = f2bf(acc[r] * 2.0f);
        Ibf[(size_t)m * 32 + 16 + lr] = 0;
    }
}

// ---------- general stage (prologue + LoRA tile 64; guard skips t>64) ----------
template<int HT>
__device__ __forceinline__ void stage_half(int t, unsigned short* region, int tid,
    const unsigned short* __restrict__ Xbf, const unsigned short* __restrict__ Wbf,
    const unsigned short* __restrict__ Ibf, const unsigned short* __restrict__ BbfA,
    const unsigned short* __restrict__ Zrow, int m0, int n0) {
    if (t > 64) return;
    #pragma unroll
    for (int j = 0; j < 2; ++j) {
        int r = j * 64 + (tid >> 3);
        int gr;
        if (HT == 0)      gr = r + (r & 64);
        else if (HT == 1) gr = 64 + r + (r & 64);
        else if (HT == 2) gr = ((r >> 5) << 6) | (r & 31);
        else              gr = (((r >> 5) << 6) | (r & 31)) + 32;
        int c = ((tid & 7) ^ (r & 7)) * 8;   // T2: 3-bit slot XOR, involution with read side
        const unsigned short* src;
        if (t < 64) {
            src = (HT <= 1 ? Xbf + (size_t)(m0 + gr) * DIN
                           : Wbf + (size_t)(n0 + gr) * DIN) + (size_t)t * 64 + c;
        } else {
            if (c >= 32) src = Zrow;  // logical cols 32..63 are zero
            else src = (HT <= 1 ? Ibf + (size_t)(m0 + gr) * 32
                                : BbfA + (size_t)(n0 + gr) * 32) + c;
        }
        gld16(src, region + r * 64 + (tid & 7) * 8);
    }
}

__device__ __forceinline__ void readA(bf16x8 (&A)[4][2], const char* p, int hk16, int xsw) {
    #pragma unroll
    for (int fi = 0; fi < 4; ++fi)
        #pragma unroll
        for (int ks = 0; ks < 2; ++ks)
            A[fi][ks] = *(const bf16x8*)(p + fi * 2048 + ((ks * 64 + hk16) ^ xsw));
}
__device__ __forceinline__ void readB(bf16x8 (&B)[2][2], const char* p, int hk16, int xsw) {
    #pragma unroll
    for (int fj = 0; fj < 2; ++fj)
        #pragma unroll
        for (int ks = 0; ks < 2; ++ks)
            B[fj][ks] = *(const bf16x8*)(p + fj * 2048 + ((ks * 64 + hk16) ^ xsw));
}

template<int RO, int CO>
__device__ __forceinline__ void quad(f32x4 (&acc)[8][4], const bf16x8 (&A)[4][2], const bf16x8 (&B)[2][2]) {
    #pragma unroll
    for (int fi = 0; fi < 4; ++fi)
        #pragma unroll
        for (int fj = 0; fj < 2; ++fj)
            #pragma unroll
            for (int ks = 0; ks < 2; ++ks)
                acc[RO + fi][CO + fj] = __builtin_amdgcn_mfma_f32_16x16x32_bf16(
                    A[fi][ks], B[fj][ks], acc[RO + fi][CO + fj], 0, 0, 0);
}

// ---------- main GEMM: 256x256 tile, BK=64, 8 waves (2x4), read-pipelined 4-phase ----------
__global__ __launch_bounds__(512, 2) void gemm8_kernel(
    const unsigned short* __restrict__ Xbf, const unsigned short* __restrict__ Wbf,
    const unsigned short* __restrict__ Ibf, const unsigned short* __restrict__ Bbf,
    const unsigned short* __restrict__ Zrow,
    const float* __restrict__ bias, const int* __restrict__ ids,
    float* __restrict__ out) {
    __shared__ unsigned short lds[2][2][2][8192];  // [buf][A/B][half][128*64]

    int tid = threadIdx.x;
    int bid = blockIdx.x;
    // bm-range XCD swizzle: XCD x = bid&7 owns bm in [8x, 8x+8), all 16 bn, bn-fastest.
    int xcd = bid & 7, q = bid >> 3;
    int bm = xcd * 8 + (q >> 4), bn = q & 15;
    int m0 = bm << 8, n0 = bn << 8;
    int aid = ids[m0 >> 9];                   // 256-row tile within one 512-row batch
    const unsigned short* BbfA = Bbf + (size_t)aid * DOUT * 32;

    int w = tid >> 6, l = tid & 63;
    int wr = w >> 2, wc = w & 3;              // 2 x 4 waves, each owns 128x64 of C
    int lr = l & 15;
    int hk16 = (l >> 4) * 16;                 // k-offset bytes per lane group
    int xsw = (l & 7) << 4;                   // read-side 3-bit slot swizzle (row&7 == l&7)

    // ---- hoisted staging addresses: 8 per-thread base pointers, +t*64 elems per tile ----
    int r0 = tid >> 3;
    int cc = ((tid & 7) ^ (r0 & 7)) * 8;      // same for j=0/1 (since (64+r0)&7 == r0&7)
    int g2 = ((r0 >> 5) << 6) | (r0 & 31);
    const unsigned short* pA0 = Xbf + (size_t)(m0 + r0) * DIN + cc;        // HT0 j0
    const unsigned short* pA1 = Xbf + (size_t)(m0 + 128 + r0) * DIN + cc;  // HT0 j1
    const unsigned short* pA2 = Xbf + (size_t)(m0 + 64 + r0) * DIN + cc;   // HT1 j0
    const unsigned short* pA3 = Xbf + (size_t)(m0 + 192 + r0) * DIN + cc;  // HT1 j1
    const unsigned short* pB0 = Wbf + (size_t)(n0 + g2) * DIN + cc;        // HT2 j0
    const unsigned short* pB1 = Wbf + (size_t)(n0 + 128 + g2) * DIN + cc;  // HT2 j1
    const unsigned short* pB2 = Wbf + (size_t)(n0 + 32 + g2) * DIN + cc;   // HT3 j0
    const unsigned short* pB3 = Wbf + (size_t)(n0 + 160 + g2) * DIN + cc;  // HT3 j1
    int dof = tid * 8;                        // linear LDS dst (gld16: base + lane*16B)

    f32x4 acc[8][4] = {};
    bf16x8 a0[4][2], a1[4][2], fb0[2][2], fb1[2][2];  // persistent fragment buffers

    // prologue: T0 complete -> buf0; T1 {A0,B0,B1} -> buf1; 3 half-tiles in flight
    stage_half<0>(0, &lds[0][0][0][0], tid, Xbf, Wbf, Ibf, BbfA, Zrow, m0, n0);
    stage_half<1>(0, &lds[0][0][1][0], tid, Xbf, Wbf, Ibf, BbfA, Zrow, m0, n0);
    stage_half<2>(0, &lds[0][1][0][0], tid, Xbf, Wbf, Ibf, BbfA, Zrow, m0, n0);
    stage_half<3>(0, &lds[0][1][1][0], tid, Xbf, Wbf, Ibf, BbfA, Zrow, m0, n0);
    stage_half<0>(1, &lds[1][0][0][0], tid, Xbf, Wbf, Ibf, BbfA, Zrow, m0, n0);
    stage_half<2>(1, &lds[1][1][0][0], tid, Xbf, Wbf, Ibf, BbfA, Zrow, m0, n0);
    stage_half<3>(1, &lds[1][1][1][0], tid, Xbf, Wbf, Ibf, BbfA, Zrow, m0, n0);
    WCNT6(); BARRIER();

    int rowA = (wr * 64 + lr) * 128;  // byte offset of this lane's A rows in a half-region
    int rowB = (wc * 32 + lr) * 128;

    // pipeline prime: a0(0), fb0(0) from buf0 (landed by prologue gate)
    readA(a0, (const char*)&lds[0][0][0][0] + rowA, hk16, xsw);
    readB(fb0, (const char*)&lds[0][1][0][0] + rowB, hk16, xsw);

    // K-tile body as a macro so peeled iterations reuse the identical phase frame.
    // S1..S4: staging statements for the 4 sites; WQ: vmcnt wait at P4.
#define KTILE_BODY(b, S1, S2, S3, S4, WQ)                                            \
    do {                                                                             \
        S1;                                                                          \
        BARRIER();                                                                   \
        LGKM0();                                                                     \
        __builtin_amdgcn_s_setprio(1);                                               \
        quad<0, 0>(acc, a0, fb0);                                                    \
        __builtin_amdgcn_s_setprio(0);                                               \
        readB(fb1, (const char*)&lds[b][1][1][0] + rowB, hk16, xsw);                 \
        BARRIER();                                                                   \
        S2;                                                                          \
        BARRIER();                                                                   \
        LGKM0();                                                                     \
        __builtin_amdgcn_s_setprio(1);                                               \
        quad<0, 2>(acc, a0, fb1);                                                    \
        __builtin_amdgcn_s_setprio(0);                                               \
        readA(a1, (const char*)&lds[b][0][1][0] + rowA, hk16, xsw);                  \
        BARRIER();                                                                   \
        S3;                                                                          \
        BARRIER();                                                                   \
        LGKM0();                                                                     \
        __builtin_amdgcn_s_setprio(1);                                               \
        quad<4, 0>(acc, a1, fb0);                                                    \
        __builtin_amdgcn_s_setprio(0);                                               \
        BARRIER();                                                                   \
        S4;                                                                          \
        WQ;                                                                          \
        BARRIER();                                                                   \
        __builtin_amdgcn_s_setprio(1);                                               \
        quad<4, 2>(acc, a1, fb1);                                                    \
        __builtin_amdgcn_s_setprio(0);                                               \
        readA(a0, (const char*)&lds[b ^ 1][0][0][0] + rowA, hk16, xsw);              \
        readB(fb0, (const char*)&lds[b ^ 1][1][0][0] + rowB, hk16, xsw);             \
        BARRIER();                                                                   \
    } while (0)

    // main loop: t in [0,62), branchless hoisted-pointer staging
    #pragma unroll 2
    for (int t = 0; t < 62; ++t) {
        int b = t & 1;
        unsigned short* dA1 = &lds[b ^ 1][0][1][0] + dof;
        unsigned short* dA0 = &lds[b][0][0][0] + dof;
        unsigned short* dB0 = &lds[b][1][0][0] + dof;
        unsigned short* dB1 = &lds[b][1][1][0] + dof;
        KTILE_BODY(b,
            { gld16(pA2 + (size_t)(t + 1) * 64, dA1); gld16(pA3 + (size_t)(t + 1) * 64, dA1 + 4096); },
            { gld16(pA0 + (size_t)(t + 2) * 64, dA0); gld16(pA1 + (size_t)(t + 2) * 64, dA0 + 4096); },
            { gld16(pB0 + (size_t)(t + 2) * 64, dB0); gld16(pB1 + (size_t)(t + 2) * 64, dB0 + 4096); },
            { gld16(pB2 + (size_t)(t + 2) * 64, dB1); gld16(pB3 + (size_t)(t + 2) * 64, dB1 + 4096); },
            WCNT6());
    }

    // t = 62 (b = 0): stages A1(63) via pointers; A0/B0/B1(64) = LoRA tile via general path
    KTILE_BODY(0,
        { gld16(pA2 + (size_t)63 * 64, &lds[1][0][1][0] + dof);
          gld16(pA3 + (size_t)63 * 64, &lds[1][0][1][0] + dof + 4096); },
        { stage_half<0>(64, &lds[0][0][0][0], tid, Xbf, Wbf, Ibf, BbfA, Zrow, m0, n0); },
        { stage_half<2>(64, &lds[0][1][0][0], tid, Xbf, Wbf, Ibf, BbfA, Zrow, m0, n0); },
        { stage_half<3>(64, &lds[0][1][1][0], tid, Xbf, Wbf, Ibf, BbfA, Zrow, m0, n0); },
        WCNT6());

    // t = 63 (b = 1): stages A1(64) = LoRA A-half1; sites 2-4 empty; full drain
    KTILE_BODY(1,
        { stage_half<1>(64, &lds[0][0][1][0], tid, Xbf, Wbf, Ibf, BbfA, Zrow, m0, n0); },
        { }, { }, { },
        WCNT0());

#undef KTILE_BODY

    // tail: LoRA K-tile 64 in buf0; a0(64), fb0(64) reads outstanding (issued end t=63)
    LGKM0();
    quad<0, 0>(acc, a0, fb0);
    readB(fb1, (const char*)&lds[0][1][1][0] + rowB, hk16, xsw);
    readA(a1, (const char*)&lds[0][0][1][0] + rowA, hk16, xsw);
    LGKM0();
    quad<0, 2>(acc, a0, fb1);
    quad<4, 0>(acc, a1, fb0);
    quad<4, 2>(acc, a1, fb1);

    // epilogue: + bias, fp32 NT store. C/D frag layout: col = lane&15, row = (lane>>4)*4 + reg
    #pragma unroll
    for (int cj = 0; cj < 4; ++cj) {
        int col = n0 + wc * 64 + cj * 16 + lr;
        float bv = bias[col];
        #pragma unroll
        for (int ri = 0; ri < 8; ++ri) {
            size_t mrow = (size_t)(m0 + wr * 128 + ri * 16 + (l >> 4) * 4);
            float* op = out + mrow * DOUT + col;
            #pragma unroll
            for (int r = 0; r < 4; ++r)
                __builtin_nontemporal_store(acc[ri][cj][r] + bv, op + (size_t)r * DOUT);
        }
    }
}

extern "C" void kernel_launch(void* const* d_in, const int* in_sizes, int n_in,
                              void* d_out, int out_size, void* d_ws, size_t ws_size,
                              hipStream_t stream) {
    const float* x     = (const float*)d_in[0];   // (32,512,4096)
    const int*   ids   = (const int*)d_in[1];     // (32,)
    const float* A_all = (const float*)d_in[2];   // (32,16,4096)
    const float* B_all = (const float*)d_in[3];   // (32,4096,16)
    const float* W     = (const float*)d_in[4];   // (4096,4096)
    const float* bias  = (const float*)d_in[5];   // (4096,)
    float* out = (float*)d_out;                   // (32,512,4096) fp32

    unsigned short* Xbf  = (unsigned short*)d_ws;            // [16384][4096]
    unsigned short* Wbf  = Xbf + (size_t)MM * DIN;           // [4096][4096]
    unsigned short* Abf  = Wbf + (size_t)DOUT * DIN;         // [32][16][4096]
    unsigned short* Bbf  = Abf + (size_t)NAD * RR * DIN;     // [32][4096][32]
    unsigned short* Ibf  = Bbf + (size_t)NAD * DOUT * 32;    // [16384][32]
    unsigned short* Zrow = Ibf + (size_t)MM * 32;            // 8 zero elems (16B)

    cvt_kernel<<<8192, 256, 0, stream>>>(x, Xbf, (long)MM * DIN);
    cvt_kernel<<<8192, 256, 0, stream>>>(W, Wbf, (long)DOUT * DIN);
    cvt_kernel<<<1024, 256, 0, stream>>>(A_all, Abf, (long)NAD * RR * DIN);
    cvt_ball_kernel<<<512, 256, 0, stream>>>(B_all, Bbf, Zrow);
    inter_kernel<<<256, 256, 0, stream>>>(Xbf, Abf, ids, Ibf);
    gemm8_kernel<<<1024, 512, 0, stream>>>(Xbf, Wbf, Ibf, Bbf, Zrow, bias, ids, out);
}

// Round 15
// 529.224 us; speedup vs baseline: 1.4759x; 1.0817x over previous
//
#include <hip/hip_runtime.h>
#include <hip/hip_bf16.h>
#include <stdint.h>

// BatchedLoRALinear: out[m][o] = sum_k x[m][k] W[o][k] + b[o] + 2*sum_r Bb[o][r] inter[m][r]
// M=16384, N=4096, K=4096 (+1 LoRA K-tile). bf16 MFMA, 256x256 tile, BK=64, 8 waves.
// R15 = R14 (475us gemm) with 5 of 8 barriers removed per K-tile. Audit: only
//   B1 (after Q1 lgkm-drain; orders a0/fb0 use before S2/S3 overwrite),
//   B3 (after Q3; orders fb1/a1 use before S4 / next S1),
//   B4 (WCNT6+barrier; staged-data cross-thread visibility)
// are load-bearing. Instruction order per wave identical to R14 — pure relaxation;
// waves drift within segments -> cross-wave MFMA/LDS overlap.

typedef __attribute__((ext_vector_type(8))) short bf16x8;
typedef __attribute__((ext_vector_type(4))) float f32x4;
typedef __attribute__((ext_vector_type(8))) unsigned short ushort8;

#define MM    16384
#define DIN   4096
#define DOUT  4096
#define RR    16
#define NAD   32

__device__ __forceinline__ unsigned short f2bf(float f) {
    union { float f; unsigned int u; } v; v.f = f;
    unsigned int r = (v.u + 0x7FFFu + ((v.u >> 16) & 1u)) >> 16;  // RNE
    return (unsigned short)r;
}

__device__ __forceinline__ void gld16(const void* g, void* l) {
    __builtin_amdgcn_global_load_lds(
        (const __attribute__((address_space(1))) void*)g,
        (__attribute__((address_space(3))) void*)l,
        16, 0, 0);
}

#define BARRIER() __builtin_amdgcn_s_barrier()
#define SFENCE()  __builtin_amdgcn_sched_barrier(0)
#define LGKM0()   do { asm volatile("s_waitcnt lgkmcnt(0)" ::: "memory"); SFENCE(); } while (0)
#define WCNT6()   asm volatile("s_waitcnt vmcnt(6)" ::: "memory")
#define WCNT0()   asm volatile("s_waitcnt vmcnt(0)" ::: "memory")

// ---------- fp32 -> bf16 bulk convert (NT loads: sources read exactly once) ----------
__global__ __launch_bounds__(256) void cvt_kernel(const float* __restrict__ src,
                                                  unsigned short* __restrict__ dst,
                                                  long n) {
    long i0 = ((long)blockIdx.x * 256 + threadIdx.x) * 8;
    long stride = (long)gridDim.x * 256 * 8;
    for (long i = i0; i < n; i += stride) {
        f32x4 f0 = __builtin_nontemporal_load((const f32x4*)(src + i));
        f32x4 f1 = __builtin_nontemporal_load((const f32x4*)(src + i + 4));
        ushort8 o;
        o[0] = f2bf(f0[0]); o[1] = f2bf(f0[1]); o[2] = f2bf(f0[2]); o[3] = f2bf(f0[3]);
        o[4] = f2bf(f1[0]); o[5] = f2bf(f1[1]); o[6] = f2bf(f1[2]); o[7] = f2bf(f1[3]);
        *(ushort8*)(dst + i) = o;
    }
}

// ---------- B_all fp32 (NAD,DOUT,16) -> bf16 [NAD][DOUT][32] (cols 16..31 zero); zero Zrow ----------
__global__ __launch_bounds__(256) void cvt_ball_kernel(const float* __restrict__ Ball,
                                                       unsigned short* __restrict__ Bbf,
                                                       unsigned short* __restrict__ Zrow) {
    int row = blockIdx.x * 256 + threadIdx.x;
    const float* s = Ball + (size_t)row * RR;
    ushort8 o0, o1, z;
    #pragma unroll
    for (int j = 0; j < 8; ++j) {
        o0[j] = f2bf(__builtin_nontemporal_load(s + j));
        o1[j] = f2bf(__builtin_nontemporal_load(s + 8 + j));
        z[j] = 0;
    }
    ushort8* d = (ushort8*)(Bbf + (size_t)row * 32);
    d[0] = o0; d[1] = o1; d[2] = z; d[3] = z;
    if (row == 0) *(ushort8*)Zrow = z;
}

// ---------- inter[m][r] = 2 * sum_k x[m][k] * A_b[r][k], bf16, padded to 32 cols ----------
__global__ __launch_bounds__(256) void inter_kernel(const unsigned short* __restrict__ Xbf,
                                                    const unsigned short* __restrict__ Abf,
                                                    const int* __restrict__ ids,
                                                    unsigned short* __restrict__ Ibf) {
    int tid = threadIdx.x, w = tid >> 6, lane = tid & 63;
    int m0 = blockIdx.x * 64 + w * 16;
    int aid = ids[m0 >> 9];
    int lr = lane & 15, lk = (lane >> 4) * 8;
    const unsigned short* xp = Xbf + (size_t)(m0 + lr) * DIN + lk;
    const unsigned short* ap = Abf + ((size_t)aid * RR + lr) * DIN + lk;
    f32x4 acc = {};
    #pragma unroll 4
    for (int k = 0; k < DIN; k += 32) {
        bf16x8 a  = *(const bf16x8*)(xp + k);
        bf16x8 bb = *(const bf16x8*)(ap + k);
        acc = __builtin_amdgcn_mfma_f32_16x16x32_bf16(a, bb, acc, 0, 0, 0);
    }
    int rbase = m0 + (lane >> 4) * 4;
    #pragma unroll
    for (int r = 0; r < 4; ++r) {
        int m = rbase + r;
        Ibf[(size_t)m * 32 + lr]      = f2bf(acc[r] * 2.0f);
        Ibf[(size_t)m * 32 + 16 + lr] = 0;
    }
}

// ---------- general stage (prologue + LoRA tile 64; guard skips t>64) ----------
template<int HT>
__device__ __forceinline__ void stage_half(int t, unsigned short* region, int tid,
    const unsigned short* __restrict__ Xbf, const unsigned short* __restrict__ Wbf,
    const unsigned short* __restrict__ Ibf, const unsigned short* __restrict__ BbfA,
    const unsigned short* __restrict__ Zrow, int m0, int n0) {
    if (t > 64) return;
    #pragma unroll
    for (int j = 0; j < 2; ++j) {
        int r = j * 64 + (tid >> 3);
        int gr;
        if (HT == 0)      gr = r + (r & 64);
        else if (HT == 1) gr = 64 + r + (r & 64);
        else if (HT == 2) gr = ((r >> 5) << 6) | (r & 31);
        else              gr = (((r >> 5) << 6) | (r & 31)) + 32;
        int c = ((tid & 7) ^ (r & 7)) * 8;   // T2: 3-bit slot XOR, involution with read side
        const unsigned short* src;
        if (t < 64) {
            src = (HT <= 1 ? Xbf + (size_t)(m0 + gr) * DIN
                           : Wbf + (size_t)(n0 + gr) * DIN) + (size_t)t * 64 + c;
        } else {
            if (c >= 32) src = Zrow;  // logical cols 32..63 are zero
            else src = (HT <= 1 ? Ibf + (size_t)(m0 + gr) * 32
                                : BbfA + (size_t)(n0 + gr) * 32) + c;
        }
        gld16(src, region + r * 64 + (tid & 7) * 8);
    }
}

__device__ __forceinline__ void readA(bf16x8 (&A)[4][2], const char* p, int hk16, int xsw) {
    #pragma unroll
    for (int fi = 0; fi < 4; ++fi)
        #pragma unroll
        for (int ks = 0; ks < 2; ++ks)
            A[fi][ks] = *(const bf16x8*)(p + fi * 2048 + ((ks * 64 + hk16) ^ xsw));
}
__device__ __forceinline__ void readB(bf16x8 (&B)[2][2], const char* p, int hk16, int xsw) {
    #pragma unroll
    for (int fj = 0; fj < 2; ++fj)
        #pragma unroll
        for (int ks = 0; ks < 2; ++ks)
            B[fj][ks] = *(const bf16x8*)(p + fj * 2048 + ((ks * 64 + hk16) ^ xsw));
}

template<int RO, int CO>
__device__ __forceinline__ void quad(f32x4 (&acc)[8][4], const bf16x8 (&A)[4][2], const bf16x8 (&B)[2][2]) {
    #pragma unroll
    for (int fi = 0; fi < 4; ++fi)
        #pragma unroll
        for (int fj = 0; fj < 2; ++fj)
            #pragma unroll
            for (int ks = 0; ks < 2; ++ks)
                acc[RO + fi][CO + fj] = __builtin_amdgcn_mfma_f32_16x16x32_bf16(
                    A[fi][ks], B[fj][ks], acc[RO + fi][CO + fj], 0, 0, 0);
}

// ---------- main GEMM: 256x256 tile, BK=64, 8 waves (2x4), 3-barrier/K-tile ----------
__global__ __launch_bounds__(512, 2) void gemm8_kernel(
    const unsigned short* __restrict__ Xbf, const unsigned short* __restrict__ Wbf,
    const unsigned short* __restrict__ Ibf, const unsigned short* __restrict__ Bbf,
    const unsigned short* __restrict__ Zrow,
    const float* __restrict__ bias, const int* __restrict__ ids,
    float* __restrict__ out) {
    __shared__ unsigned short lds[2][2][2][8192];  // [buf][A/B][half][128*64]

    int tid = threadIdx.x;
    int bid = blockIdx.x;
    // bm-range XCD swizzle: XCD x = bid&7 owns bm in [8x, 8x+8), all 16 bn, bn-fastest.
    int xcd = bid & 7, q = bid >> 3;
    int bm = xcd * 8 + (q >> 4), bn = q & 15;
    int m0 = bm << 8, n0 = bn << 8;
    int aid = ids[m0 >> 9];                   // 256-row tile within one 512-row batch
    const unsigned short* BbfA = Bbf + (size_t)aid * DOUT * 32;

    int w = tid >> 6, l = tid & 63;
    int wr = w >> 2, wc = w & 3;              // 2 x 4 waves, each owns 128x64 of C
    int lr = l & 15;
    int hk16 = (l >> 4) * 16;                 // k-offset bytes per lane group
    int xsw = (l & 7) << 4;                   // read-side 3-bit slot swizzle (row&7 == l&7)

    // ---- hoisted staging addresses: 8 per-thread base pointers, +t*64 elems per tile ----
    int r0 = tid >> 3;
    int cc = ((tid & 7) ^ (r0 & 7)) * 8;      // same for j=0/1 (since (64+r0)&7 == r0&7)
    int g2 = ((r0 >> 5) << 6) | (r0 & 31);
    const unsigned short* pA0 = Xbf + (size_t)(m0 + r0) * DIN + cc;        // HT0 j0
    const unsigned short* pA1 = Xbf + (size_t)(m0 + 128 + r0) * DIN + cc;  // HT0 j1
    const unsigned short* pA2 = Xbf + (size_t)(m0 + 64 + r0) * DIN + cc;   // HT1 j0
    const unsigned short* pA3 = Xbf + (size_t)(m0 + 192 + r0) * DIN + cc;  // HT1 j1
    const unsigned short* pB0 = Wbf + (size_t)(n0 + g2) * DIN + cc;        // HT2 j0
    const unsigned short* pB1 = Wbf + (size_t)(n0 + 128 + g2) * DIN + cc;  // HT2 j1
    const unsigned short* pB2 = Wbf + (size_t)(n0 + 32 + g2) * DIN + cc;   // HT3 j0
    const unsigned short* pB3 = Wbf + (size_t)(n0 + 160 + g2) * DIN + cc;  // HT3 j1
    int dof = tid * 8;                        // linear LDS dst (gld16: base + lane*16B)

    f32x4 acc[8][4] = {};
    bf16x8 a0[4][2], a1[4][2], fb0[2][2], fb1[2][2];  // persistent fragment buffers

    // prologue: T0 complete -> buf0; T1 {A0,B0,B1} -> buf1; 3 half-tiles in flight
    stage_half<0>(0, &lds[0][0][0][0], tid, Xbf, Wbf, Ibf, BbfA, Zrow, m0, n0);
    stage_half<1>(0, &lds[0][0][1][0], tid, Xbf, Wbf, Ibf, BbfA, Zrow, m0, n0);
    stage_half<2>(0, &lds[0][1][0][0], tid, Xbf, Wbf, Ibf, BbfA, Zrow, m0, n0);
    stage_half<3>(0, &lds[0][1][1][0], tid, Xbf, Wbf, Ibf, BbfA, Zrow, m0, n0);
    stage_half<0>(1, &lds[1][0][0][0], tid, Xbf, Wbf, Ibf, BbfA, Zrow, m0, n0);
    stage_half<2>(1, &lds[1][1][0][0], tid, Xbf, Wbf, Ibf, BbfA, Zrow, m0, n0);
    stage_half<3>(1, &lds[1][1][1][0], tid, Xbf, Wbf, Ibf, BbfA, Zrow, m0, n0);
    WCNT6(); BARRIER();

    int rowA = (wr * 64 + lr) * 128;  // byte offset of this lane's A rows in a half-region
    int rowB = (wc * 32 + lr) * 128;

    // pipeline prime: a0(0), fb0(0) from buf0 (landed by prologue gate)
    readA(a0, (const char*)&lds[0][0][0][0] + rowA, hk16, xsw);
    readB(fb0, (const char*)&lds[0][1][0][0] + rowB, hk16, xsw);

    // 3-barrier K-tile frame. S1..S4: staging statements; WQ: vmcnt wait at the gate.
#define KTILE_BODY(b, S1, S2, S3, S4, WQ)                                            \
    do {                                                                             \
        S1;                                                                          \
        LGKM0();                      /* drain a0,fb0 (read end of prev gate) */     \
        __builtin_amdgcn_s_setprio(1);                                               \
        quad<0, 0>(acc, a0, fb0);                                                    \
        __builtin_amdgcn_s_setprio(0);                                               \
        readB(fb1, (const char*)&lds[b][1][1][0] + rowB, hk16, xsw);                 \
        BARRIER();                    /* B1: a0/fb0 consumed -> S2/S3 may overwrite */\
        S2;                                                                          \
        LGKM0();                      /* drain fb1 */                                \
        __builtin_amdgcn_s_setprio(1);                                               \
        quad<0, 2>(acc, a0, fb1);                                                    \
        __builtin_amdgcn_s_setprio(0);                                               \
        readA(a1, (const char*)&lds[b][0][1][0] + rowA, hk16, xsw);                  \
        S3;                                                                          \
        LGKM0();                      /* drain a1 */                                 \
        __builtin_amdgcn_s_setprio(1);                                               \
        quad<4, 0>(acc, a1, fb0);                                                    \
        __builtin_amdgcn_s_setprio(0);                                               \
        BARRIER();                    /* B3: fb1/a1 consumed -> S4 / next S1 safe */ \
        S4;                                                                          \
        WQ;                                                                          \
        BARRIER();                    /* B4: staged tile t+1 visible to all */       \
        __builtin_amdgcn_s_setprio(1);                                               \
        quad<4, 2>(acc, a1, fb1);                                                    \
        __builtin_amdgcn_s_setprio(0);                                               \
        readA(a0, (const char*)&lds[b ^ 1][0][0][0] + rowA, hk16, xsw);              \
        readB(fb0, (const char*)&lds[b ^ 1][1][0][0] + rowB, hk16, xsw);             \
    } while (0)

    // main loop: t in [0,62), branchless hoisted-pointer staging
    #pragma unroll 2
    for (int t = 0; t < 62; ++t) {
        int b = t & 1;
        unsigned short* dA1 = &lds[b ^ 1][0][1][0] + dof;
        unsigned short* dA0 = &lds[b][0][0][0] + dof;
        unsigned short* dB0 = &lds[b][1][0][0] + dof;
        unsigned short* dB1 = &lds[b][1][1][0] + dof;
        KTILE_BODY(b,
            { gld16(pA2 + (size_t)(t + 1) * 64, dA1); gld16(pA3 + (size_t)(t + 1) * 64, dA1 + 4096); },
            { gld16(pA0 + (size_t)(t + 2) * 64, dA0); gld16(pA1 + (size_t)(t + 2) * 64, dA0 + 4096); },
            { gld16(pB0 + (size_t)(t + 2) * 64, dB0); gld16(pB1 + (size_t)(t + 2) * 64, dB0 + 4096); },
            { gld16(pB2 + (size_t)(t + 2) * 64, dB1); gld16(pB3 + (size_t)(t + 2) * 64, dB1 + 4096); },
            WCNT6());
    }

    // t = 62 (b = 0): stages A1(63) via pointers; A0/B0/B1(64) = LoRA tile via general path
    KTILE_BODY(0,
        { gld16(pA2 + (size_t)63 * 64, &lds[1][0][1][0] + dof);
          gld16(pA3 + (size_t)63 * 64, &lds[1][0][1][0] + dof + 4096); },
        { stage_half<0>(64, &lds[0][0][0][0], tid, Xbf, Wbf, Ibf, BbfA, Zrow, m0, n0); },
        { stage_half<2>(64, &lds[0][1][0][0], tid, Xbf, Wbf, Ibf, BbfA, Zrow, m0, n0); },
        { stage_half<3>(64, &lds[0][1][1][0], tid, Xbf, Wbf, Ibf, BbfA, Zrow, m0, n0); },
        WCNT6());

    // t = 63 (b = 1): stages A1(64) = LoRA A-half1; sites 2-4 empty; full drain
    KTILE_BODY(1,
        { stage_half<1>(64, &lds[0][0][1][0], tid, Xbf, Wbf, Ibf, BbfA, Zrow, m0, n0); },
        { }, { }, { },
        WCNT0());

#undef KTILE_BODY

    // tail: LoRA K-tile 64 in buf0; a0(64), fb0(64) reads outstanding (issued end t=63)
    LGKM0();
    quad<0, 0>(acc, a0, fb0);
    readB(fb1, (const char*)&lds[0][1][1][0] + rowB, hk16, xsw);
    readA(a1, (const char*)&lds[0][0][1][0] + rowA, hk16, xsw);
    LGKM0();
    quad<0, 2>(acc, a0, fb1);
    quad<4, 0>(acc, a1, fb0);
    quad<4, 2>(acc, a1, fb1);

    // epilogue: + bias, fp32 NT store. C/D frag layout: col = lane&15, row = (lane>>4)*4 + reg
    #pragma unroll
    for (int cj = 0; cj < 4; ++cj) {
        int col = n0 + wc * 64 + cj * 16 + lr;
        float bv = bias[col];
        #pragma unroll
        for (int ri = 0; ri < 8; ++ri) {
            size_t mrow = (size_t)(m0 + wr * 128 + ri * 16 + (l >> 4) * 4);
            float* op = out + mrow * DOUT + col;
            #pragma unroll
            for (int r = 0; r < 4; ++r)
                __builtin_nontemporal_store(acc[ri][cj][r] + bv, op + (size_t)r * DOUT);
        }
    }
}

extern "C" void kernel_launch(void* const* d_in, const int* in_sizes, int n_in,
                              void* d_out, int out_size, void* d_ws, size_t ws_size,
                              hipStream_t stream) {
    const float* x     = (const float*)d_in[0];   // (32,512,4096)
    const int*   ids   = (const int*)d_in[1];     // (32,)
    const float* A_all = (const float*)d_in[2];   // (32,16,4096)
    const float* B_all = (const float*)d_in[3];   // (32,4096,16)
    const float* W     = (const float*)d_in[4];   // (4096,4096)
    const float* bias  = (const float*)d_in[5];   // (4096,)
    float* out = (float*)d_out;                   // (32,512,4096) fp32

    unsigned short* Xbf  = (unsigned short*)d_ws;            // [16384][4096]
    unsigned short* Wbf  = Xbf + (size_t)MM * DIN;           // [4096][4096]
    unsigned short* Abf  = Wbf + (size_t)DOUT * DIN;         // [32][16][4096]
    unsigned short* Bbf  = Abf + (size_t)NAD * RR * DIN;     // [32][4096][32]
    unsigned short* Ibf  = Bbf + (size_t)NAD * DOUT * 32;    // [16384][32]
    unsigned short* Zrow = Ibf + (size_t)MM * 32;            // 8 zero elems (16B)

    cvt_kernel<<<8192, 256, 0, stream>>>(x, Xbf, (long)MM * DIN);
    cvt_kernel<<<8192, 256, 0, stream>>>(W, Wbf, (long)DOUT * DIN);
    cvt_kernel<<<1024, 256, 0, stream>>>(A_all, Abf, (long)NAD * RR * DIN);
    cvt_ball_kernel<<<512, 256, 0, stream>>>(B_all, Bbf, Zrow);
    inter_kernel<<<256, 256, 0, stream>>>(Xbf, Abf, ids, Ibf);
    gemm8_kernel<<<1024, 512, 0, stream>>>(Xbf, Wbf, Ibf, Bbf, Zrow, bias, ids, out);
}